// Round 16
// baseline (883.597 us; speedup 1.0000x reference)
//
#include <hip/hip_runtime.h>
#include <cstdint>
#include <cstddef>

static constexpr int NN = 50000;     // nodes
static constexpr int NE = 1600000;   // edges
static constexpr int NG = 64;        // graphs
static constexpr int FE = 16;        // edge feature dim

typedef float f32x2 __attribute__((ext_vector_type(2)));
typedef float f32x4 __attribute__((ext_vector_type(4)));

// ---- fused node linear: xl = h@Wl + bl, xr = h@Wr + br ----
template<int DIN, int DOUT>
__global__ __launch_bounds__(256) void k_node_linear(
    const float* __restrict__ h,
    const float* __restrict__ Wl, const float* __restrict__ bl,
    const float* __restrict__ Wr, const float* __restrict__ br,
    float* __restrict__ xl, float* __restrict__ xr)
{
    __shared__ float sW[2 * DIN * DOUT];
    __shared__ float sX[16 * DIN];
    const int n0 = blockIdx.x * 16;

    for (int i = threadIdx.x; i < DIN * DOUT; i += 256) {
        sW[i] = Wl[i];
        sW[DIN * DOUT + i] = Wr[i];
    }
    for (int i = threadIdx.x; i < 16 * DIN; i += 256) {
        int r = i / DIN, k = i % DIN;
        int n = n0 + r;
        sX[i] = (n < NN) ? h[(size_t)n * DIN + k] : 0.0f;
    }
    __syncthreads();

    constexpr int NQ = DOUT / 4;     // output quads per node
    for (int o = threadIdx.x; o < 16 * NQ; o += 256) {
        const int r = o / NQ, d0 = 4 * (o % NQ);
        const int n = n0 + r;
        if (n >= NN) continue;
        f32x4 accl = *(const f32x4*)(bl + d0);
        f32x4 accr = *(const f32x4*)(br + d0);
        #pragma unroll 4
        for (int k = 0; k < DIN; ++k) {
            const float xv = sX[r * DIN + k];
            accl += xv * *(const f32x4*)(sW + k * DOUT + d0);
            accr += xv * *(const f32x4*)(sW + DIN * DOUT + k * DOUT + d0);
        }
        *(f32x4*)(xl + (size_t)n * DOUT + d0) = accl;
        *(f32x4*)(xr + (size_t)n * DOUT + d0) = accr;
    }
}

// ---- CSR build: count / scan / fill ----
__global__ __launch_bounds__(256) void k_count(
    const int* __restrict__ ei, int* __restrict__ cnt)
{
    const int e = blockIdx.x * 256 + threadIdx.x;
    if (e >= NE) return;
    atomicAdd(cnt + ei[NE + e], 1);
}

__global__ __launch_bounds__(1024) void k_scan(
    const int* __restrict__ cnt, int* __restrict__ rowptr)
{
    __shared__ int part[1024];
    const int T = 1024;
    const int C = (NN + T - 1) / T;
    const int t = threadIdx.x;
    const int base = t * C;
    int s = 0;
    for (int i = 0; i < C; ++i) {
        int idx = base + i;
        if (idx < NN) s += cnt[idx];
    }
    part[t] = s;
    __syncthreads();
    for (int off = 1; off < T; off <<= 1) {
        int v = 0;
        if (t >= off) v = part[t - off];
        __syncthreads();
        if (t >= off) part[t] += v;
        __syncthreads();
    }
    int run = (t == 0) ? 0 : part[t - 1];
    for (int i = 0; i < C; ++i) {
        int idx = base + i;
        if (idx < NN) { rowptr[idx] = run; run += cnt[idx]; }
    }
    if (t == T - 1) rowptr[NN] = run;
}

// one 8B packed store per edge: {src, edge_id}
__global__ __launch_bounds__(256) void k_fill(
    const int* __restrict__ ei, const int* __restrict__ rowptr,
    int* __restrict__ woff, int2* __restrict__ epack)
{
    const int e = blockIdx.x * 256 + threadIdx.x;
    if (e >= NE) return;
    const int dst = ei[NE + e];
    const int pos = rowptr[dst] + atomicAdd(woff + dst, 1);
    epack[pos] = make_int2(ei[e], e);
}

// ---- fused GATv2: score + online softmax + aggregate + bias + relu ----
// [PROVEN STRUCTURE — one node/wave, zero LDS, shfl_xor merge, defer-max
//  THR=8, int2 epack, D>=64 wave-wide scalar-pipe addressing, DPL==2
//  dim-pair f32x2 packing (natural layout, VGPR-safe — R15).]
// This rev: wave-wide path processes edges in CHUNKS of 8 — adjacent
// wave-uniform epack reads merge into s_load_dwordx8/x16, the 8 xl row
// loads issue immediately (independent SGPR-base), and the 8 ea s_load
// chains rotate under the unrolled score/update body. One index-latency
// round-trip per 8 edges instead of per 2 (R15: 63% VALUBusy = the
// latency chain, not VALU count, is now the critical path).
template<int D>
__global__ __launch_bounds__(128, 4) void k_gat_fused(
    const int* __restrict__ rowptr, const int2* __restrict__ epack,
    const float* __restrict__ eaf,
    const float* __restrict__ xl, const float* __restrict__ xr,
    const float* __restrict__ We, const float* __restrict__ att,
    const float* __restrict__ bo, float* __restrict__ hout)
{
    constexpr int DPL = (D >= 64) ? (D / 64) : 2;   // dims per lane
    constexpr int SW  = D / DPL;                    // stream width in lanes
    constexpr int EPW = 64 / SW;                    // edge streams per wave
    constexpr int WPB = 2;                          // waves (=nodes) per block
    constexpr int CH  = 8;                          // chunk (wave-wide path)

    const int wave = threadIdx.x >> 6;
    const int lane = threadIdx.x & 63;
    const int n = blockIdx.x * WPB + wave;
    if (n >= NN) return;
    const int sub = lane / SW;
    const int dl  = lane % SW;
    const int d0  = DPL * dl;      // owned dims {d0 .. d0+DPL-1}

    // register-resident weights / per-node dest transform
    f32x2 rWe2[DPL == 2 ? FE : 1];   // natural dim-pair layout (DPL==2)
    float rWe1[DPL == 1 ? FE : 1];   // scalar (DPL==1)
    float rAtt[DPL], rXr[DPL], acc[DPL];
    #pragma unroll
    for (int i = 0; i < DPL; ++i) {
        rAtt[i] = att[d0 + i];
        rXr[i]  = xr[(size_t)n * D + d0 + i];
        acc[i]  = 0.f;
    }
    if constexpr (DPL == 2) {
        #pragma unroll
        for (int k = 0; k < FE; ++k)
            rWe2[k] = *(const f32x2*)(We + k * D + d0);
    } else {
        #pragma unroll
        for (int k = 0; k < FE; ++k)
            rWe1[k] = We[k * D + d0];
    }

    int p0 = rowptr[n], p1 = rowptr[n + 1];
    if constexpr (SW == 64) {
        p0 = __builtin_amdgcn_readfirstlane(p0);
        p1 = __builtin_amdgcn_readfirstlane(p1);
    }
    float m = -3.4e38f, l = 0.f;

    auto score_edge = [&](const float (&eav)[FE], const float (&rXl)[DPL]) -> float {
        float sv;
        if constexpr (DPL == 2) {
            f32x2 mm = (f32x2){rXl[0] + rXr[0], rXl[1] + rXr[1]};
            #pragma unroll
            for (int k = 0; k < FE; ++k) {
                const f32x2 ee = (f32x2){eav[k], eav[k]};
                mm += ee * rWe2[k];          // v_pk_fma_f32
            }
            float m0 = mm.x, m1 = mm.y;
            m0 = fmaxf(m0, 0.2f * m0);       // leaky_relu, slope<1
            m1 = fmaxf(m1, 0.2f * m1);
            sv = fmaf(m0, rAtt[0], m1 * rAtt[1]);
        } else {
            float mm = rXl[0] + rXr[0];
            #pragma unroll
            for (int k = 0; k < FE; ++k)
                mm = fmaf(eav[k], rWe1[k], mm);
            mm = fmaxf(mm, 0.2f * mm);
            sv = mm * rAtt[0];
        }
        #pragma unroll
        for (int off = 1; off < SW; off <<= 1) sv += __shfl_xor(sv, off);
        return sv;
    };
    auto sm_update = [&](float sv, const float (&rXl)[DPL]) {
        const float dd = sv - m;
        float wexp;
        if (__builtin_expect(dd > 8.f, 0)) {
            // rare: max grew by >8 -> rescale (exp(-dd)=0 handles first edge)
            const float r = __expf(-dd);
            #pragma unroll
            for (int i = 0; i < DPL; ++i) acc[i] *= r;
            l *= r; m = sv; wexp = 1.f;
        } else {
            wexp = __expf(dd);   // bounded by e^8
        }
        #pragma unroll
        for (int i = 0; i < DPL; ++i) acc[i] = fmaf(wexp, rXl[i], acc[i]);
        l += wexp;
    };

    if constexpr (SW == 64) {
        // ---- wave-wide stream: 8-edge chunks, batched scalar index loads ----
        int p = p0;
        for (; p + CH <= p1; p += CH) {
            int ss[CH], ee[CH];
            #pragma unroll
            for (int j = 0; j < CH; ++j) {
                const int2 se = epack[p + j];          // adjacent uniform loads
                ss[j] = __builtin_amdgcn_readfirstlane(se.x);
                ee[j] = __builtin_amdgcn_readfirstlane(se.y);
            }
            float rXl[CH][DPL];
            #pragma unroll
            for (int j = 0; j < CH; ++j)
                #pragma unroll
                for (int i = 0; i < DPL; ++i)
                    rXl[j][i] = xl[(size_t)ss[j] * D + d0 + i];
            #pragma unroll
            for (int j = 0; j < CH; ++j) {
                float eav[FE];
                const float* ep = eaf + (size_t)(unsigned)ee[j] * FE;
                #pragma unroll
                for (int k = 0; k < FE; ++k) eav[k] = ep[k];
                sm_update(score_edge(eav, rXl[j]), rXl[j]);
            }
        }
        for (; p < p1; ++p) {                          // tail
            const int2 se = epack[p];
            const int s    = __builtin_amdgcn_readfirstlane(se.x);
            const int erow = __builtin_amdgcn_readfirstlane(se.y);
            float eav[FE], rXl[DPL];
            #pragma unroll
            for (int i = 0; i < DPL; ++i)
                rXl[i] = xl[(size_t)s * D + d0 + i];
            const float* ep = eaf + (size_t)(unsigned)erow * FE;
            #pragma unroll
            for (int k = 0; k < FE; ++k) eav[k] = ep[k];
            sm_update(score_edge(eav, rXl), rXl);
        }
    } else {
        // ---- sub-wave streams (D=32): proven 2-edge-unroll path ----
        auto load_edge = [&](int p, float (&eav)[FE], float (&rXl)[DPL]) {
            const int2 se = epack[p];
            #pragma unroll
            for (int i = 0; i < DPL; ++i)
                rXl[i] = xl[(size_t)se.x * D + d0 + i];
            const float* ep = eaf + (size_t)se.y * FE;
            #pragma unroll
            for (int k4 = 0; k4 < 4; ++k4) {
                const float4 v = *(const float4*)(ep + 4 * k4);
                eav[4 * k4]     = v.x; eav[4 * k4 + 1] = v.y;
                eav[4 * k4 + 2] = v.z; eav[4 * k4 + 3] = v.w;
            }
        };
        int p = p0 + sub;
        for (; p + EPW < p1; p += 2 * EPW) {
            float eavA[FE], rXlA[DPL], eavB[FE], rXlB[DPL];
            load_edge(p, eavA, rXlA);
            load_edge(p + EPW, eavB, rXlB);
            const float svA = score_edge(eavA, rXlA);
            const float svB = score_edge(eavB, rXlB);
            sm_update(svA, rXlA);
            sm_update(svB, rXlB);
        }
        if (p < p1) {
            float eav[FE], rXl[DPL];
            load_edge(p, eav, rXl);
            sm_update(score_edge(eav, rXl), rXl);
        }
    }

    // ---- merge the EPW streams via shfl_xor cascade (no-op when EPW==1) ----
    #pragma unroll
    for (int step = SW; step < 64; step <<= 1) {
        const float mo = __shfl_xor(m, step);
        const float mstar = fmaxf(m, mo);
        const float sc = __expf(m - mstar);   // ==1 when m==mstar (incl. empty)
        #pragma unroll
        for (int i = 0; i < DPL; ++i) acc[i] *= sc;
        l *= sc;
        #pragma unroll
        for (int i = 0; i < DPL; ++i) acc[i] += __shfl_xor(acc[i], step);
        l += __shfl_xor(l, step);
        m = mstar;
    }

    if (lane < SW) {
        const float inv = 1.0f / (l + 1e-16f);
        #pragma unroll
        for (int i = 0; i < DPL; ++i)
            hout[(size_t)n * D + d0 + i] = fmaxf(fmaf(acc[i], inv, bo[d0 + i]), 0.f);
    }
}

// ---- global mean pool: run-length reduction over sorted batch ----
__global__ __launch_bounds__(128) void k_pool(
    const float* __restrict__ h, const int* __restrict__ batch,
    float* __restrict__ pooled, float* __restrict__ cnt)
{
    constexpr int BLOCKS = 512;
    constexpr int CH = (NN + BLOCKS - 1) / BLOCKS;
    const int t = threadIdx.x;
    const int n0 = blockIdx.x * CH;
    const int n1 = min(NN, n0 + CH);
    if (n0 >= n1) return;

    int g = batch[n0];
    float acc = 0.f, c = 0.f;
    for (int n = n0; n < n1; ++n) {
        const int bg = batch[n];
        if (bg != g) {
            atomicAdd(pooled + g * 128 + t, acc);
            if (t == 0) atomicAdd(cnt + g, c);
            acc = 0.f; c = 0.f; g = bg;
        }
        acc += h[(size_t)n * 128 + t];
        c += 1.f;
    }
    atomicAdd(pooled + g * 128 + t, acc);
    if (t == 0) atomicAdd(cnt + g, c);
}

// ---- dueling heads ----
__global__ __launch_bounds__(128) void k_head(
    const float* __restrict__ pooled, const float* __restrict__ cnt,
    const float* __restrict__ Wv1, const float* __restrict__ bv1,
    const float* __restrict__ Wv2, const float* __restrict__ bv2,
    const float* __restrict__ Wa1, const float* __restrict__ ba1,
    const float* __restrict__ Wa2, const float* __restrict__ ba2,
    float* __restrict__ out)
{
    __shared__ float pr[128];
    __shared__ float hv[64];
    __shared__ float ha[64];
    __shared__ float sA[10];
    __shared__ float sVM[2];
    const int g = blockIdx.x;
    const int t = threadIdx.x;

    const float inv = 1.0f / fmaxf(cnt[g], 1.0f);
    pr[t] = pooled[g * 128 + t] * inv;
    __syncthreads();

    if (t < 64) {
        float sv = bv1[t], sa = ba1[t];
        #pragma unroll 8
        for (int k = 0; k < 128; ++k) {
            float p = pr[k];
            sv = fmaf(p, Wv1[k * 64 + t], sv);
            sa = fmaf(p, Wa1[k * 64 + t], sa);
        }
        hv[t] = fmaxf(sv, 0.0f);
        ha[t] = fmaxf(sa, 0.0f);
    }
    __syncthreads();

    if (t < 10) {
        float av = ba2[t];
        #pragma unroll
        for (int j = 0; j < 64; ++j) av = fmaf(ha[j], Wa2[j * 10 + t], av);
        sA[t] = av;
    }
    if (t == 64) {
        float v = bv2[0];
        #pragma unroll
        for (int j = 0; j < 64; ++j) v = fmaf(hv[j], Wv2[j], v);
        sVM[0] = v;
    }
    __syncthreads();

    if (t == 0) {
        float s = 0.0f;
        #pragma unroll
        for (int j = 0; j < 10; ++j) s += sA[j];
        sVM[1] = s * 0.1f;
    }
    __syncthreads();

    if (t < 10) out[g * 10 + t] = sVM[0] + sA[t] - sVM[1];
}

extern "C" void kernel_launch(void* const* d_in, const int* in_sizes, int n_in,
                              void* d_out, int out_size, void* d_ws, size_t ws_size,
                              hipStream_t stream)
{
    const float* x     = (const float*)d_in[0];
    const float* ea    = (const float*)d_in[1];
    const int*   ei    = (const int*)d_in[2];   // [2*E], row0 = src, row1 = dst
    const int*   batch = (const int*)d_in[3];

    // workspace layout
    float* ws = (float*)d_ws;
    float* xl     = ws;                              // N*128
    float* xr     = xl + (size_t)NN * 128;           // N*128
    float* hA     = xr + (size_t)NN * 128;           // N*128 (layer1 out D=32, layer3 out D=128)
    float* hB     = hA + (size_t)NN * 128;           // N*64  (layer2 out D=64)
    float* pooled = hB + (size_t)NN * 64;            // G*128
    float* cntp   = pooled + (size_t)NG * 128;       // G
    int*   rowptr = (int*)(cntp + NG);               // NN+1
    int*   cnt    = rowptr + (NN + 1);               // NN
    int*   woff   = cnt + NN;                        // NN   (contiguous with cnt)
    int*   pad    = woff + NN;                       // +1 -> 8B alignment for int2
    int2*  epack  = (int2*)(pad + 1);                // NE ({src, eid} per CSR slot)

    const int EB = (NE + 255) / 256;

    // ---- CSR by destination (shared across all 3 layers) ----
    hipMemsetAsync(cnt, 0, 2 * NN * sizeof(int), stream);   // cnt + woff
    k_count<<<dim3(EB), dim3(256), 0, stream>>>(ei, cnt);
    k_scan<<<dim3(1), dim3(1024), 0, stream>>>(cnt, rowptr);
    k_fill<<<dim3(EB), dim3(256), 0, stream>>>(ei, rowptr, woff, epack);

    const int GB = (NN + 1) / 2;   // 2 nodes per block (1 per wave)

#define LAYER(DIN, DOUT, HIN, HOUT, B)                                                   \
    do {                                                                                 \
        k_node_linear<DIN, DOUT><<<dim3((NN + 15) / 16), dim3(256), 0, stream>>>(        \
            HIN, (const float*)d_in[B], (const float*)d_in[(B) + 1],                     \
            (const float*)d_in[(B) + 2], (const float*)d_in[(B) + 3], xl, xr);           \
        k_gat_fused<DOUT><<<dim3(GB), dim3(128), 0, stream>>>(                           \
            rowptr, epack, ea, xl, xr, (const float*)d_in[(B) + 4],                      \
            (const float*)d_in[(B) + 5], (const float*)d_in[(B) + 6], HOUT);             \
    } while (0)

    LAYER(128, 32, x,  hA, 4);    // layer 1: 128 -> 32
    LAYER(32,  64, hA, hB, 11);   // layer 2: 32  -> 64
    LAYER(64, 128, hB, hA, 18);   // layer 3: 64  -> 128

#undef LAYER

    hipMemsetAsync(pooled, 0, (NG * 128 + NG) * sizeof(float), stream);  // pooled + cntp
    k_pool<<<dim3(512), dim3(128), 0, stream>>>(hA, batch, pooled, cntp);
    k_head<<<dim3(NG), dim3(128), 0, stream>>>(
        pooled, cntp,
        (const float*)d_in[25], (const float*)d_in[26],
        (const float*)d_in[27], (const float*)d_in[28],
        (const float*)d_in[29], (const float*)d_in[30],
        (const float*)d_in[31], (const float*)d_in[32],
        (float*)d_out);
}

// Round 17
// 828.217 us; speedup vs baseline: 1.0669x; 1.0669x over previous
//
#include <hip/hip_runtime.h>
#include <cstdint>
#include <cstddef>

static constexpr int NN = 50000;     // nodes
static constexpr int NE = 1600000;   // edges
static constexpr int NG = 64;        // graphs
static constexpr int FE = 16;        // edge feature dim

typedef float f32x2 __attribute__((ext_vector_type(2)));
typedef float f32x4 __attribute__((ext_vector_type(4)));

// ---- fused node linear: xl = h@Wl + bl, xr = h@Wr + br ----
template<int DIN, int DOUT>
__global__ __launch_bounds__(256) void k_node_linear(
    const float* __restrict__ h,
    const float* __restrict__ Wl, const float* __restrict__ bl,
    const float* __restrict__ Wr, const float* __restrict__ br,
    float* __restrict__ xl, float* __restrict__ xr)
{
    __shared__ float sW[2 * DIN * DOUT];
    __shared__ float sX[16 * DIN];
    const int n0 = blockIdx.x * 16;

    for (int i = threadIdx.x; i < DIN * DOUT; i += 256) {
        sW[i] = Wl[i];
        sW[DIN * DOUT + i] = Wr[i];
    }
    for (int i = threadIdx.x; i < 16 * DIN; i += 256) {
        int r = i / DIN, k = i % DIN;
        int n = n0 + r;
        sX[i] = (n < NN) ? h[(size_t)n * DIN + k] : 0.0f;
    }
    __syncthreads();

    constexpr int NQ = DOUT / 4;     // output quads per node
    for (int o = threadIdx.x; o < 16 * NQ; o += 256) {
        const int r = o / NQ, d0 = 4 * (o % NQ);
        const int n = n0 + r;
        if (n >= NN) continue;
        f32x4 accl = *(const f32x4*)(bl + d0);
        f32x4 accr = *(const f32x4*)(br + d0);
        #pragma unroll 4
        for (int k = 0; k < DIN; ++k) {
            const float xv = sX[r * DIN + k];
            accl += xv * *(const f32x4*)(sW + k * DOUT + d0);
            accr += xv * *(const f32x4*)(sW + DIN * DOUT + k * DOUT + d0);
        }
        *(f32x4*)(xl + (size_t)n * DOUT + d0) = accl;
        *(f32x4*)(xr + (size_t)n * DOUT + d0) = accr;
    }
}

// ---- CSR build: count / scan / fill ----
__global__ __launch_bounds__(256) void k_count(
    const int* __restrict__ ei, int* __restrict__ cnt)
{
    const int e = blockIdx.x * 256 + threadIdx.x;
    if (e >= NE) return;
    atomicAdd(cnt + ei[NE + e], 1);
}

__global__ __launch_bounds__(1024) void k_scan(
    const int* __restrict__ cnt, int* __restrict__ rowptr)
{
    __shared__ int part[1024];
    const int T = 1024;
    const int C = (NN + T - 1) / T;
    const int t = threadIdx.x;
    const int base = t * C;
    int s = 0;
    for (int i = 0; i < C; ++i) {
        int idx = base + i;
        if (idx < NN) s += cnt[idx];
    }
    part[t] = s;
    __syncthreads();
    for (int off = 1; off < T; off <<= 1) {
        int v = 0;
        if (t >= off) v = part[t - off];
        __syncthreads();
        if (t >= off) part[t] += v;
        __syncthreads();
    }
    int run = (t == 0) ? 0 : part[t - 1];
    for (int i = 0; i < C; ++i) {
        int idx = base + i;
        if (idx < NN) { rowptr[idx] = run; run += cnt[idx]; }
    }
    if (t == T - 1) rowptr[NN] = run;
}

// one 8B packed store per edge: {src, edge_id}
__global__ __launch_bounds__(256) void k_fill(
    const int* __restrict__ ei, const int* __restrict__ rowptr,
    int* __restrict__ woff, int2* __restrict__ epack)
{
    const int e = blockIdx.x * 256 + threadIdx.x;
    if (e >= NE) return;
    const int dst = ei[NE + e];
    const int pos = rowptr[dst] + atomicAdd(woff + dst, 1);
    epack[pos] = make_int2(ei[e], e);
}

// ---- fused GATv2: score + online softmax + aggregate + bias + relu ----
// [PROVEN BEST CONFIG (R15, 194us@D=128) — do not re-break:
//  * one node/wave, zero LDS, shfl_xor merge, defer-max THR=8, int2 epack
//  * D>=64: wave-wide scalar-pipe addressing (readfirstlane -> s_loads)
//  * DPL==2: dim-pair f32x2 packing (natural load layout, VGPR-safe);
//    k-axis packing spills (R9 asm, R11 ext-vec: VGPR 52-56, ~2x slower)
//  * 2-edge unroll is the SGPR-capacity limit: 2x16 eav sets + bases ~= 96
//    SGPR; 8-deep chunking (R16) forced eav out of SGPRs -> serialized
//    s_load chains, occupancy 68->60, L3 194->228us.]
template<int D>
__global__ __launch_bounds__(128, 4) void k_gat_fused(
    const int* __restrict__ rowptr, const int2* __restrict__ epack,
    const float* __restrict__ eaf,
    const float* __restrict__ xl, const float* __restrict__ xr,
    const float* __restrict__ We, const float* __restrict__ att,
    const float* __restrict__ bo, float* __restrict__ hout)
{
    constexpr int DPL = (D >= 64) ? (D / 64) : 2;   // dims per lane
    constexpr int SW  = D / DPL;                    // stream width in lanes
    constexpr int EPW = 64 / SW;                    // edge streams per wave
    constexpr int WPB = 2;                          // waves (=nodes) per block

    const int wave = threadIdx.x >> 6;
    const int lane = threadIdx.x & 63;
    const int n = blockIdx.x * WPB + wave;
    if (n >= NN) return;
    const int sub = lane / SW;
    const int dl  = lane % SW;
    const int d0  = DPL * dl;      // owned dims {d0 .. d0+DPL-1}

    // register-resident weights / per-node dest transform
    f32x2 rWe2[DPL == 2 ? FE : 1];   // natural dim-pair layout (DPL==2)
    float rWe1[DPL == 1 ? FE : 1];   // scalar (DPL==1)
    float rAtt[DPL], rXr[DPL], acc[DPL];
    #pragma unroll
    for (int i = 0; i < DPL; ++i) {
        rAtt[i] = att[d0 + i];
        rXr[i]  = xr[(size_t)n * D + d0 + i];
        acc[i]  = 0.f;
    }
    if constexpr (DPL == 2) {
        #pragma unroll
        for (int k = 0; k < FE; ++k)
            rWe2[k] = *(const f32x2*)(We + k * D + d0);
    } else {
        #pragma unroll
        for (int k = 0; k < FE; ++k)
            rWe1[k] = We[k * D + d0];
    }

    int p0 = rowptr[n], p1 = rowptr[n + 1];
    if constexpr (SW == 64) {
        p0 = __builtin_amdgcn_readfirstlane(p0);
        p1 = __builtin_amdgcn_readfirstlane(p1);
    }
    float m = -3.4e38f, l = 0.f;

    auto load_edge = [&](int p, float (&eav)[FE], float (&rXl)[DPL]) {
        const int2 se = epack[p];
        if constexpr (SW == 64) {
            // whole edge stream is wave-uniform: scalar index/feature loads,
            // SGPR-base row accesses (per-lane part is the fixed d0 offset)
            const int s    = __builtin_amdgcn_readfirstlane(se.x);
            const int erow = __builtin_amdgcn_readfirstlane(se.y);
            #pragma unroll
            for (int i = 0; i < DPL; ++i)
                rXl[i] = xl[(size_t)s * D + d0 + i];
            const float* ep = eaf + (size_t)(unsigned)erow * FE;
            #pragma unroll
            for (int k = 0; k < FE; ++k) eav[k] = ep[k];
        } else {
            #pragma unroll
            for (int i = 0; i < DPL; ++i)
                rXl[i] = xl[(size_t)se.x * D + d0 + i];
            // same address across the stream's lanes -> broadcast fetch
            const float* ep = eaf + (size_t)se.y * FE;
            #pragma unroll
            for (int k4 = 0; k4 < 4; ++k4) {
                const float4 v = *(const float4*)(ep + 4 * k4);
                eav[4 * k4]     = v.x; eav[4 * k4 + 1] = v.y;
                eav[4 * k4 + 2] = v.z; eav[4 * k4 + 3] = v.w;
            }
        }
    };
    auto score_edge = [&](const float (&eav)[FE], const float (&rXl)[DPL]) -> float {
        float sv;
        if constexpr (DPL == 2) {
            f32x2 mm = (f32x2){rXl[0] + rXr[0], rXl[1] + rXr[1]};
            #pragma unroll
            for (int k = 0; k < FE; ++k) {
                const f32x2 ee = (f32x2){eav[k], eav[k]};
                mm += ee * rWe2[k];          // v_pk_fma_f32
            }
            float m0 = mm.x, m1 = mm.y;
            m0 = fmaxf(m0, 0.2f * m0);       // leaky_relu, slope<1
            m1 = fmaxf(m1, 0.2f * m1);
            sv = fmaf(m0, rAtt[0], m1 * rAtt[1]);
        } else {
            float mm = rXl[0] + rXr[0];
            #pragma unroll
            for (int k = 0; k < FE; ++k)
                mm = fmaf(eav[k], rWe1[k], mm);
            mm = fmaxf(mm, 0.2f * mm);
            sv = mm * rAtt[0];
        }
        #pragma unroll
        for (int off = 1; off < SW; off <<= 1) sv += __shfl_xor(sv, off);
        return sv;
    };
    auto sm_update = [&](float sv, const float (&rXl)[DPL]) {
        const float dd = sv - m;
        float wexp;
        if (__builtin_expect(dd > 8.f, 0)) {
            // rare: max grew by >8 -> rescale (exp(-dd)=0 handles first edge)
            const float r = __expf(-dd);
            #pragma unroll
            for (int i = 0; i < DPL; ++i) acc[i] *= r;
            l *= r; m = sv; wexp = 1.f;
        } else {
            wexp = __expf(dd);   // bounded by e^8
        }
        #pragma unroll
        for (int i = 0; i < DPL; ++i) acc[i] = fmaf(wexp, rXl[i], acc[i]);
        l += wexp;
    };

    int p = p0 + sub;
    for (; p + EPW < p1; p += 2 * EPW) {
        float eavA[FE], rXlA[DPL], eavB[FE], rXlB[DPL];
        load_edge(p, eavA, rXlA);
        load_edge(p + EPW, eavB, rXlB);
        const float svA = score_edge(eavA, rXlA);
        const float svB = score_edge(eavB, rXlB);
        sm_update(svA, rXlA);
        sm_update(svB, rXlB);
    }
    if (p < p1) {
        float eav[FE], rXl[DPL];
        load_edge(p, eav, rXl);
        sm_update(score_edge(eav, rXl), rXl);
    }

    // ---- merge the EPW streams via shfl_xor cascade (no-op when EPW==1) ----
    #pragma unroll
    for (int step = SW; step < 64; step <<= 1) {
        const float mo = __shfl_xor(m, step);
        const float mstar = fmaxf(m, mo);
        const float sc = __expf(m - mstar);   // ==1 when m==mstar (incl. empty)
        #pragma unroll
        for (int i = 0; i < DPL; ++i) acc[i] *= sc;
        l *= sc;
        #pragma unroll
        for (int i = 0; i < DPL; ++i) acc[i] += __shfl_xor(acc[i], step);
        l += __shfl_xor(l, step);
        m = mstar;
    }

    if (lane < SW) {
        const float inv = 1.0f / (l + 1e-16f);
        #pragma unroll
        for (int i = 0; i < DPL; ++i)
            hout[(size_t)n * D + d0 + i] = fmaxf(fmaf(acc[i], inv, bo[d0 + i]), 0.f);
    }
}

// ---- global mean pool: run-length reduction over sorted batch ----
__global__ __launch_bounds__(128) void k_pool(
    const float* __restrict__ h, const int* __restrict__ batch,
    float* __restrict__ pooled, float* __restrict__ cnt)
{
    constexpr int BLOCKS = 512;
    constexpr int CH = (NN + BLOCKS - 1) / BLOCKS;
    const int t = threadIdx.x;
    const int n0 = blockIdx.x * CH;
    const int n1 = min(NN, n0 + CH);
    if (n0 >= n1) return;

    int g = batch[n0];
    float acc = 0.f, c = 0.f;
    for (int n = n0; n < n1; ++n) {
        const int bg = batch[n];
        if (bg != g) {
            atomicAdd(pooled + g * 128 + t, acc);
            if (t == 0) atomicAdd(cnt + g, c);
            acc = 0.f; c = 0.f; g = bg;
        }
        acc += h[(size_t)n * 128 + t];
        c += 1.f;
    }
    atomicAdd(pooled + g * 128 + t, acc);
    if (t == 0) atomicAdd(cnt + g, c);
}

// ---- dueling heads ----
__global__ __launch_bounds__(128) void k_head(
    const float* __restrict__ pooled, const float* __restrict__ cnt,
    const float* __restrict__ Wv1, const float* __restrict__ bv1,
    const float* __restrict__ Wv2, const float* __restrict__ bv2,
    const float* __restrict__ Wa1, const float* __restrict__ ba1,
    const float* __restrict__ Wa2, const float* __restrict__ ba2,
    float* __restrict__ out)
{
    __shared__ float pr[128];
    __shared__ float hv[64];
    __shared__ float ha[64];
    __shared__ float sA[10];
    __shared__ float sVM[2];
    const int g = blockIdx.x;
    const int t = threadIdx.x;

    const float inv = 1.0f / fmaxf(cnt[g], 1.0f);
    pr[t] = pooled[g * 128 + t] * inv;
    __syncthreads();

    if (t < 64) {
        float sv = bv1[t], sa = ba1[t];
        #pragma unroll 8
        for (int k = 0; k < 128; ++k) {
            float p = pr[k];
            sv = fmaf(p, Wv1[k * 64 + t], sv);
            sa = fmaf(p, Wa1[k * 64 + t], sa);
        }
        hv[t] = fmaxf(sv, 0.0f);
        ha[t] = fmaxf(sa, 0.0f);
    }
    __syncthreads();

    if (t < 10) {
        float av = ba2[t];
        #pragma unroll
        for (int j = 0; j < 64; ++j) av = fmaf(ha[j], Wa2[j * 10 + t], av);
        sA[t] = av;
    }
    if (t == 64) {
        float v = bv2[0];
        #pragma unroll
        for (int j = 0; j < 64; ++j) v = fmaf(hv[j], Wv2[j], v);
        sVM[0] = v;
    }
    __syncthreads();

    if (t == 0) {
        float s = 0.0f;
        #pragma unroll
        for (int j = 0; j < 10; ++j) s += sA[j];
        sVM[1] = s * 0.1f;
    }
    __syncthreads();

    if (t < 10) out[g * 10 + t] = sVM[0] + sA[t] - sVM[1];
}

extern "C" void kernel_launch(void* const* d_in, const int* in_sizes, int n_in,
                              void* d_out, int out_size, void* d_ws, size_t ws_size,
                              hipStream_t stream)
{
    const float* x     = (const float*)d_in[0];
    const float* ea    = (const float*)d_in[1];
    const int*   ei    = (const int*)d_in[2];   // [2*E], row0 = src, row1 = dst
    const int*   batch = (const int*)d_in[3];

    // workspace layout
    float* ws = (float*)d_ws;
    float* xl     = ws;                              // N*128
    float* xr     = xl + (size_t)NN * 128;           // N*128
    float* hA     = xr + (size_t)NN * 128;           // N*128 (layer1 out D=32, layer3 out D=128)
    float* hB     = hA + (size_t)NN * 128;           // N*64  (layer2 out D=64)
    float* pooled = hB + (size_t)NN * 64;            // G*128
    float* cntp   = pooled + (size_t)NG * 128;       // G
    int*   rowptr = (int*)(cntp + NG);               // NN+1
    int*   cnt    = rowptr + (NN + 1);               // NN
    int*   woff   = cnt + NN;                        // NN   (contiguous with cnt)
    int*   pad    = woff + NN;                       // +1 -> 8B alignment for int2
    int2*  epack  = (int2*)(pad + 1);                // NE ({src, eid} per CSR slot)

    const int EB = (NE + 255) / 256;

    // ---- CSR by destination (shared across all 3 layers) ----
    hipMemsetAsync(cnt, 0, 2 * NN * sizeof(int), stream);   // cnt + woff
    k_count<<<dim3(EB), dim3(256), 0, stream>>>(ei, cnt);
    k_scan<<<dim3(1), dim3(1024), 0, stream>>>(cnt, rowptr);
    k_fill<<<dim3(EB), dim3(256), 0, stream>>>(ei, rowptr, woff, epack);

    const int GB = (NN + 1) / 2;   // 2 nodes per block (1 per wave)

#define LAYER(DIN, DOUT, HIN, HOUT, B)                                                   \
    do {                                                                                 \
        k_node_linear<DIN, DOUT><<<dim3((NN + 15) / 16), dim3(256), 0, stream>>>(        \
            HIN, (const float*)d_in[B], (const float*)d_in[(B) + 1],                     \
            (const float*)d_in[(B) + 2], (const float*)d_in[(B) + 3], xl, xr);           \
        k_gat_fused<DOUT><<<dim3(GB), dim3(128), 0, stream>>>(                           \
            rowptr, epack, ea, xl, xr, (const float*)d_in[(B) + 4],                      \
            (const float*)d_in[(B) + 5], (const float*)d_in[(B) + 6], HOUT);             \
    } while (0)

    LAYER(128, 32, x,  hA, 4);    // layer 1: 128 -> 32
    LAYER(32,  64, hA, hB, 11);   // layer 2: 32  -> 64
    LAYER(64, 128, hB, hA, 18);   // layer 3: 64  -> 128

#undef LAYER

    hipMemsetAsync(pooled, 0, (NG * 128 + NG) * sizeof(float), stream);  // pooled + cntp
    k_pool<<<dim3(512), dim3(128), 0, stream>>>(hA, batch, pooled, cntp);
    k_head<<<dim3(NG), dim3(128), 0, stream>>>(
        pooled, cntp,
        (const float*)d_in[25], (const float*)d_in[26],
        (const float*)d_in[27], (const float*)d_in[28],
        (const float*)d_in[29], (const float*)d_in[30],
        (const float*)d_in[31], (const float*)d_in[32],
        (float*)d_out);
}